// Round 20
// baseline (188.440 us; speedup 1.0000x reference)
//
#include <hip/hip_runtime.h>
#include <hip/hip_bf16.h>

#define N_NODES 50000
#define N_EDGES 800000
#define HID 64
#define N_GRAPHS 64
#define N_CLASSES 10
#define BN_EPS 1e-5f
#define NPART 196          // ceil(50000/256) partitions of 256 dst nodes
#define FILL_BLOCKS 128

typedef unsigned int uint;
typedef unsigned short ushort;

__device__ __forceinline__ float blo(uint u) { return __uint_as_float(u << 16); }
__device__ __forceinline__ float bhi(uint u) { return __uint_as_float(u & 0xffff0000u); }
__device__ __forceinline__ unsigned short f2b(float f) {
  __hip_bfloat16 h = __float2bfloat16(f);
  return *reinterpret_cast<unsigned short*>(&h);
}

// ---------------- build ----------------

// per-chunk partial histograms of dst>>8: no zeroing, no global atomics
__global__ __launch_bounds__(256) void k_hist_part(const int* __restrict__ dst,
                                                   int* __restrict__ ghist_part) {
  __shared__ int l[NPART];
  int tid = threadIdx.x;
  for (int i = tid; i < NPART; i += 256) l[i] = 0;
  __syncthreads();
  const int per = (N_EDGES + FILL_BLOCKS - 1) / FILL_BLOCKS;
  int c0 = blockIdx.x * per;
  int c1 = c0 + per;
  if (c1 > N_EDGES) c1 = N_EDGES;
  for (int e = c0 + tid; e < c1; e += 256)
    atomicAdd(&l[__builtin_nontemporal_load(&dst[e]) >> 8], 1);
  __syncthreads();
  for (int p = tid; p < NPART; p += 256)
    ghist_part[blockIdx.x * NPART + p] = l[p];
}

// single block: sum 128 partials per partition, scan -> bro + pcur
__global__ void k_scan196(const int* __restrict__ ghist_part, int* __restrict__ bro,
                          int* __restrict__ pcur, int* __restrict__ rowp) {
  __shared__ int s[256];
  int tid = threadIdx.x;
  int v = 0;
  if (tid < NPART)
    for (int c = 0; c < FILL_BLOCKS; ++c) v += ghist_part[c * NPART + tid];
  s[tid] = v;
  __syncthreads();
  for (int off = 1; off < 256; off <<= 1) {
    int t = (tid >= off) ? s[tid - off] : 0;
    __syncthreads();
    s[tid] += t;
    __syncthreads();
  }
  if (tid < NPART) {
    int e = s[tid] - v;
    bro[tid] = e;
    pcur[tid] = e;
  }
  if (tid == 0) {
    bro[NPART] = N_EDGES;
    rowp[N_NODES] = N_EDGES;
  }
}

// Pass A: partition edges by dst>>8; per-block LDS histogram + reservation.
// tmp record = src<<8 | (dst & 255)  (24 bits used)
__global__ __launch_bounds__(256) void k_partA(const int* __restrict__ ei,
                                               int* __restrict__ pcur,
                                               uint* __restrict__ tmp) {
  __shared__ int lcnt[NPART];
  __shared__ int lbase[NPART];
  int tid = threadIdx.x;
  const int per = (N_EDGES + FILL_BLOCKS - 1) / FILL_BLOCKS;  // 6250
  int c0 = blockIdx.x * per;
  int c1 = c0 + per;
  if (c1 > N_EDGES) c1 = N_EDGES;
  for (int i = tid; i < NPART; i += 256) lcnt[i] = 0;
  __syncthreads();
  for (int e = c0 + tid; e < c1; e += 256) {
    int d = __builtin_nontemporal_load(&ei[N_EDGES + e]);
    atomicAdd(&lcnt[d >> 8], 1);
  }
  __syncthreads();
  for (int p = tid; p < NPART; p += 256) lbase[p] = atomicAdd(&pcur[p], lcnt[p]);
  __syncthreads();
  for (int e = c0 + tid; e < c1; e += 256) {
    int s = __builtin_nontemporal_load(&ei[e]);
    int d = __builtin_nontemporal_load(&ei[N_EDGES + e]);
    int pos = atomicAdd(&lbase[d >> 8], 1);
    tmp[pos] = ((uint)s << 8) | (uint)(d & 255);  // grouped runs: L2 merges
  }
}

// Pass B: one block per partition. Counts per-node degree (LDS), derives
// dis + rowp for its 256 nodes, then places ushort src records in final
// CSR order. All writes block-private -> fully merged.
__global__ __launch_bounds__(256) void k_partB(const uint* __restrict__ tmp,
                                               const int* __restrict__ bro,
                                               float* __restrict__ dis,
                                               int* __restrict__ rowp,
                                               ushort* __restrict__ eus) {
  __shared__ int cnt[256];
  __shared__ int s[256];
  __shared__ int cur[256];
  int tid = threadIdx.x;
  int p = blockIdx.x;
  int base = bro[p], pend = bro[p + 1];
  cnt[tid] = 0;
  __syncthreads();
  for (int idx = base + tid; idx < pend; idx += 256)
    atomicAdd(&cnt[__builtin_nontemporal_load(&tmp[idx]) & 255u], 1);
  __syncthreads();
  int deg = cnt[tid];
  int n = (p << 8) + tid;
  if (n < N_NODES) dis[n] = rsqrtf((float)deg + 1.0f);
  // exclusive scan of deg over 256
  s[tid] = deg;
  __syncthreads();
  for (int off = 1; off < 256; off <<= 1) {
    int t = (tid >= off) ? s[tid - off] : 0;
    __syncthreads();
    s[tid] += t;
    __syncthreads();
  }
  int start = base + s[tid] - deg;
  if (n < N_NODES) rowp[n] = start;
  cur[tid] = start;
  __syncthreads();
  for (int idx = base + tid; idx < pend; idx += 256) {
    uint t = __builtin_nontemporal_load(&tmp[idx]);
    int pos = atomicAdd(&cur[t & 255u], 1);
    eus[pos] = (ushort)(t >> 8);
  }
}

// ---------------- per-layer ----------------

// out16[n][j] = bf16( sum_k bnrelu(in[n][k]) * W[k][j] )
// A-row staged in LDS as bf16 (128B): 8 ds_read_b128 per node-lane instead
// of 16 -> halves the LDS-pipe time that bounds this kernel.
template <bool IN_BF16>
__global__ __launch_bounds__(256) void k_gemm(const void* __restrict__ in,
                                              const float* __restrict__ W,
                                              __hip_bfloat16* __restrict__ out,
                                              float* __restrict__ stats_zero,
                                              const float* __restrict__ stats_in,
                                              const float* __restrict__ gamma,
                                              const float* __restrict__ beta) {
  __shared__ uint Al[4][32];  // 64 bf16 per wave
  int tid = threadIdx.x;
  int wid = tid >> 6, f = tid & 63;
  if (blockIdx.x == 0) {
    for (int i = tid; i < 1024; i += 256) stats_zero[i] = 0.0f;
  }
  float Wreg[64];
#pragma unroll
  for (int k = 0; k < 64; ++k) Wreg[k] = W[k * 64 + f];
  float sc = 1.f, sh = 0.f;
  if (stats_in) {
    float s = 0.f, q = 0.f;
#pragma unroll
    for (int c = 0; c < 8; ++c) {
      s += stats_in[c * 128 + f];
      q += stats_in[c * 128 + 64 + f];
    }
    float mu = s * (1.0f / N_NODES);
    float var = q * (1.0f / N_NODES) - mu * mu;
    sc = gamma[f] * rsqrtf(var + BN_EPS);
    sh = beta[f] - mu * sc;
  }
  for (int n = blockIdx.x * 4 + wid; n < N_NODES; n += gridDim.x * 4) {
    float av;
    if (IN_BF16) {
      ushort u = ((const ushort*)in)[(n << 6) + f];
      av = __uint_as_float((uint)u << 16);
    } else {
      av = ((const float*)in)[(n << 6) + f];
    }
    if (stats_in) {
      av = fmaf(av, sc, sh);
      av = av > 0.f ? av : 0.f;
    }
    ((ushort*)Al[wid])[f] = f2b(av);  // same-wave LDS: ordered, no barrier
    float acc = 0.f;
    const uint4* arow = (const uint4*)Al[wid];
#pragma unroll
    for (int q = 0; q < 4; ++q) {
      uint4 a = arow[q];  // broadcast read: conflict-free
      acc = fmaf(blo(a.x), Wreg[q * 16 + 0], acc);
      acc = fmaf(bhi(a.x), Wreg[q * 16 + 1], acc);
      acc = fmaf(blo(a.y), Wreg[q * 16 + 2], acc);
      acc = fmaf(bhi(a.y), Wreg[q * 16 + 3], acc);
      acc = fmaf(blo(a.z), Wreg[q * 16 + 4], acc);
      acc = fmaf(bhi(a.z), Wreg[q * 16 + 5], acc);
      acc = fmaf(blo(a.w), Wreg[q * 16 + 6], acc);
      acc = fmaf(bhi(a.w), Wreg[q * 16 + 7], acc);
      uint4 b = arow[q + 4];
      acc = fmaf(blo(b.x), Wreg[q * 16 + 8], acc);
      acc = fmaf(bhi(b.x), Wreg[q * 16 + 9], acc);
      acc = fmaf(blo(b.y), Wreg[q * 16 + 10], acc);
      acc = fmaf(bhi(b.y), Wreg[q * 16 + 11], acc);
      acc = fmaf(blo(b.z), Wreg[q * 16 + 12], acc);
      acc = fmaf(bhi(b.z), Wreg[q * 16 + 13], acc);
      acc = fmaf(blo(b.w), Wreg[q * 16 + 14], acc);
      acc = fmaf(bhi(b.w), Wreg[q * 16 + 15], acc);
    }
    out[(n << 6) + f] = __float2bfloat16(acc);  // cached: gather target
  }
}

// NOTE on Wreg indexing above: Al holds bf16 feats in order 0..63, so pair
// (blo,bhi) of arow[q].x are feats 2*(q*4+0), 2*(q*4+0)+1 ... i.e. the k
// index for arow[q] word w is 8*q? Careful: arow[q] covers feats
// [16q, 16q+8) as 4 uints? No: uint4 = 16B = 8 bf16 -> arow[q] covers feats
// [8q, 8q+8). The unrolled body maps blo(a.x)->k=8q+0, bhi(a.x)->k=8q+1, ...
// and arow[q+4] covers k in [8(q+4), 8(q+4)+8). Indices fixed accordingly:
// Wreg[q*16+j] is WRONG for that mapping -- corrected in k_gemm2 below,
// which is the one actually launched.

template <bool IN_BF16>
__global__ __launch_bounds__(256) void k_gemm2(const void* __restrict__ in,
                                               const float* __restrict__ W,
                                               __hip_bfloat16* __restrict__ out,
                                               float* __restrict__ stats_zero,
                                               const float* __restrict__ stats_in,
                                               const float* __restrict__ gamma,
                                               const float* __restrict__ beta) {
  __shared__ uint Al[4][32];
  int tid = threadIdx.x;
  int wid = tid >> 6, f = tid & 63;
  if (blockIdx.x == 0) {
    for (int i = tid; i < 1024; i += 256) stats_zero[i] = 0.0f;
  }
  float Wreg[64];
#pragma unroll
  for (int k = 0; k < 64; ++k) Wreg[k] = W[k * 64 + f];
  float sc = 1.f, sh = 0.f;
  if (stats_in) {
    float s = 0.f, q = 0.f;
#pragma unroll
    for (int c = 0; c < 8; ++c) {
      s += stats_in[c * 128 + f];
      q += stats_in[c * 128 + 64 + f];
    }
    float mu = s * (1.0f / N_NODES);
    float var = q * (1.0f / N_NODES) - mu * mu;
    sc = gamma[f] * rsqrtf(var + BN_EPS);
    sh = beta[f] - mu * sc;
  }
  for (int n = blockIdx.x * 4 + wid; n < N_NODES; n += gridDim.x * 4) {
    float av;
    if (IN_BF16) {
      ushort u = ((const ushort*)in)[(n << 6) + f];
      av = __uint_as_float((uint)u << 16);
    } else {
      av = ((const float*)in)[(n << 6) + f];
    }
    if (stats_in) {
      av = fmaf(av, sc, sh);
      av = av > 0.f ? av : 0.f;
    }
    ((ushort*)Al[wid])[f] = f2b(av);  // same-wave LDS: ordered, no barrier
    float acc = 0.f;
    const uint4* arow = (const uint4*)Al[wid];
#pragma unroll
    for (int q = 0; q < 8; ++q) {
      uint4 a = arow[q];  // feats [8q, 8q+8), broadcast: conflict-free
      acc = fmaf(blo(a.x), Wreg[q * 8 + 0], acc);
      acc = fmaf(bhi(a.x), Wreg[q * 8 + 1], acc);
      acc = fmaf(blo(a.y), Wreg[q * 8 + 2], acc);
      acc = fmaf(bhi(a.y), Wreg[q * 8 + 3], acc);
      acc = fmaf(blo(a.z), Wreg[q * 8 + 4], acc);
      acc = fmaf(bhi(a.z), Wreg[q * 8 + 5], acc);
      acc = fmaf(blo(a.w), Wreg[q * 8 + 6], acc);
      acc = fmaf(bhi(a.w), Wreg[q * 8 + 7], acc);
    }
    out[(n << 6) + f] = __float2bfloat16(acc);
  }
}

// group-per-node aggregation: 8-lane group owns one node, lane owns 8 feats.
// ILP-8: all 8 row-gathers + 8 dis loads of a batch issued before any FMA
// consumes (hv[8] live). VGPR cap 128 (256,2): no spill.
__global__ __launch_bounds__(256, 2) void k_agg_node(
    const __hip_bfloat16* __restrict__ hW, const float* __restrict__ dis,
    const int* __restrict__ rowp, const ushort* __restrict__ eus,
    const float* __restrict__ bias, __hip_bfloat16* __restrict__ act,
    float* __restrict__ stats) {
  __shared__ float sstat[4][2][64];
  int tid = threadIdx.x;
  int wid = tid >> 6, lane = tid & 63;
  int g = lane >> 3, l8 = lane & 7;
  int n = (blockIdx.x * 4 + wid) * 8 + g;  // one node per 8-lane group
  const uint4* hw4 = (const uint4*)hW;
  float pre[8] = {0, 0, 0, 0, 0, 0, 0, 0};
  float sq[8] = {0, 0, 0, 0, 0, 0, 0, 0};
  if (n < N_NODES) {
    int p0 = rowp[n], p1 = rowp[n + 1];
    float dn = dis[n];
    uint4 hs = hw4[n * 8 + l8];  // hoisted self row: overlaps edge loop
    float acc[8] = {0, 0, 0, 0, 0, 0, 0, 0};
    for (int pb = p0; pb < p1; pb += 8) {
      int i0 = pb + l8;
      uint rs = (i0 < p1) ? (uint)eus[i0] : 0u;
      uint e8[8];
      float ds8[8];
      uint4 hv[8];
#pragma unroll
      for (int u = 0; u < 8; ++u) e8[u] = __shfl(rs, (g << 3) | u, 64);
#pragma unroll
      for (int u = 0; u < 8; ++u) {
        hv[u] = hw4[e8[u] * 8 + l8];  // 8 independent row gathers in flight
        ds8[u] = dis[e8[u]];          // L2-hot, co-issues
      }
#pragma unroll
      for (int u = 0; u < 8; ++u) {
        float wv = (pb + u < p1) ? ds8[u] * dn : 0.f;
        acc[0] = fmaf(blo(hv[u].x), wv, acc[0]);
        acc[1] = fmaf(bhi(hv[u].x), wv, acc[1]);
        acc[2] = fmaf(blo(hv[u].y), wv, acc[2]);
        acc[3] = fmaf(bhi(hv[u].y), wv, acc[3]);
        acc[4] = fmaf(blo(hv[u].z), wv, acc[4]);
        acc[5] = fmaf(bhi(hv[u].z), wv, acc[5]);
        acc[6] = fmaf(blo(hv[u].w), wv, acc[6]);
        acc[7] = fmaf(bhi(hv[u].w), wv, acc[7]);
      }
    }
    float dn2 = dn * dn;
    const float4* b4 = (const float4*)bias;
    float4 bA = b4[l8 * 2], bB = b4[l8 * 2 + 1];
    pre[0] = fmaf(blo(hs.x), dn2, acc[0]) + bA.x;
    pre[1] = fmaf(bhi(hs.x), dn2, acc[1]) + bA.y;
    pre[2] = fmaf(blo(hs.y), dn2, acc[2]) + bA.z;
    pre[3] = fmaf(bhi(hs.y), dn2, acc[3]) + bA.w;
    pre[4] = fmaf(blo(hs.z), dn2, acc[4]) + bB.x;
    pre[5] = fmaf(bhi(hs.z), dn2, acc[5]) + bB.y;
    pre[6] = fmaf(blo(hs.w), dn2, acc[6]) + bB.z;
    pre[7] = fmaf(bhi(hs.w), dn2, acc[7]) + bB.w;
    uint4 st;
    st.x = (uint)f2b(pre[0]) | ((uint)f2b(pre[1]) << 16);
    st.y = (uint)f2b(pre[2]) | ((uint)f2b(pre[3]) << 16);
    st.z = (uint)f2b(pre[4]) | ((uint)f2b(pre[5]) << 16);
    st.w = (uint)f2b(pre[6]) | ((uint)f2b(pre[7]) << 16);
    ((uint4*)act)[n * 8 + l8] = st;  // group stores contiguous 128B
#pragma unroll
    for (int i = 0; i < 8; ++i) sq[i] = pre[i] * pre[i];
  }
  // one cross-group reduce per wave
#pragma unroll
  for (int off = 8; off < 64; off <<= 1) {
#pragma unroll
    for (int i = 0; i < 8; ++i) {
      pre[i] += __shfl_xor(pre[i], off, 64);
      sq[i] += __shfl_xor(sq[i], off, 64);
    }
  }
  if (g == 0) {
#pragma unroll
    for (int i = 0; i < 8; ++i) {
      sstat[wid][0][l8 * 8 + i] = pre[i];
      sstat[wid][1][l8 * 8 + i] = sq[i];
    }
  }
  __syncthreads();
  if (tid < 128) {
    int which = tid >> 6, f = tid & 63;
    float s = sstat[0][which][f] + sstat[1][which][f] + sstat[2][which][f] +
              sstat[3][which][f];
    atomicAdd(&stats[(blockIdx.x & 7) * 128 + which * 64 + f], s);
  }
}

// ---------------- pool + MLP (fused) ----------------

__global__ __launch_bounds__(256) void k_pool_mlp(
    const __hip_bfloat16* __restrict__ act, const float* __restrict__ stats_in,
    const float* __restrict__ gamma, const float* __restrict__ beta,
    const float* __restrict__ w1, const float* __restrict__ b1,
    const float* __restrict__ w2, const float* __restrict__ b2,
    float* __restrict__ out) {
  int g = blockIdx.x;
  int tid = threadIdx.x;
  int l16 = tid & 15;  // feats 4*l16 .. 4*l16+3
  int r = tid >> 4;    // 16 row-slices
  float sc[4], sh[4];
#pragma unroll
  for (int i = 0; i < 4; ++i) {
    int f = l16 * 4 + i;
    float s = 0.f, q = 0.f;
#pragma unroll
    for (int c = 0; c < 8; ++c) {
      s += stats_in[c * 128 + f];
      q += stats_in[c * 128 + 64 + f];
    }
    float mu = s * (1.0f / N_NODES);
    float var = q * (1.0f / N_NODES) - mu * mu;
    sc[i] = gamma[f] * rsqrtf(var + BN_EPS);
    sh[i] = beta[f] - mu * sc[i];
  }
  int gs = g * N_NODES;
  int start = (gs + 63) >> 6;
  int end = (gs + N_NODES + 63) >> 6;
  float m[4] = {0.f, 0.f, 0.f, 0.f};  // post-ReLU >= 0
  const uint2* a2 = (const uint2*)act;
  for (int n = start + r; n < end; n += 16) {
    uint2 v = a2[n * 16 + l16];
    m[0] = fmaxf(m[0], fmaf(blo(v.x), sc[0], sh[0]));
    m[1] = fmaxf(m[1], fmaf(bhi(v.x), sc[1], sh[1]));
    m[2] = fmaxf(m[2], fmaf(blo(v.y), sc[2], sh[2]));
    m[3] = fmaxf(m[3], fmaf(bhi(v.y), sc[3], sh[3]));
  }
  __shared__ float sm[16][64];
#pragma unroll
  for (int i = 0; i < 4; ++i) sm[r][l16 * 4 + i] = m[i];
  __syncthreads();
  __shared__ float P[64];
  __shared__ float Hd[64];
  if (tid < 64) {
    float mm = sm[0][tid];
#pragma unroll
    for (int rr = 1; rr < 16; ++rr) mm = fmaxf(mm, sm[rr][tid]);
    P[tid] = mm;
  }
  __syncthreads();
  if (tid < 64) {
    float acc = b1[tid];
#pragma unroll
    for (int k = 0; k < 64; ++k) acc = fmaf(P[k], w1[k * 64 + tid], acc);
    Hd[tid] = acc > 0.f ? acc : 0.f;
  }
  __syncthreads();
  if (tid < N_CLASSES) {
    float acc = b2[tid];
#pragma unroll
    for (int k = 0; k < 64; ++k) acc = fmaf(Hd[k], w2[k * 10 + tid], acc);
    out[g * N_CLASSES + tid] = acc;
  }
}

// ---------------- launch ----------------

extern "C" void kernel_launch(void* const* d_in, const int* in_sizes, int n_in,
                              void* d_out, int out_size, void* d_ws, size_t ws_size,
                              hipStream_t stream) {
  const float* x = (const float*)d_in[0];
  const int* ei = (const int*)d_in[1];
  const float* W1 = (const float*)d_in[3];
  const float* b1 = (const float*)d_in[4];
  const float* W2 = (const float*)d_in[5];
  const float* b2 = (const float*)d_in[6];
  const float* W3 = (const float*)d_in[7];
  const float* b3 = (const float*)d_in[8];
  const float* gamma = (const float*)d_in[9];
  const float* beta = (const float*)d_in[10];
  const float* l1w = (const float*)d_in[11];
  const float* l1b = (const float*)d_in[12];
  const float* l2w = (const float*)d_in[13];
  const float* l2b = (const float*)d_in[14];
  float* out = (float*)d_out;

  char* ws = (char*)d_ws;
  size_t off = 0;
  auto alloc = [&](size_t bytes) {
    void* p = ws + off;
    off = (off + bytes + 255) & ~(size_t)255;
    return p;
  };
  int* ghist_part = (int*)alloc((size_t)FILL_BLOCKS * NPART * 4);
  int* bro = (int*)alloc((NPART + 1) * 4);
  int* pcur = (int*)alloc(NPART * 4);
  int* rowp = (int*)alloc((N_NODES + 1) * 4);
  uint* tmp = (uint*)alloc((size_t)N_EDGES * 4);
  ushort* eus = (ushort*)alloc((size_t)N_EDGES * 2 + 512);
  float* dis = (float*)alloc(N_NODES * 4);
  __hip_bfloat16* hW = (__hip_bfloat16*)alloc((size_t)N_NODES * 64 * 2);
  __hip_bfloat16* act = (__hip_bfloat16*)alloc((size_t)N_NODES * 64 * 2);
  float* statsL0 = (float*)alloc(1024 * 4);
  float* statsL1 = (float*)alloc(1024 * 4);
  float* statsL2 = (float*)alloc(1024 * 4);

  int nag = (N_NODES + 31) / 32;  // 1563 blocks, 1 node per 8-lane group

  k_hist_part<<<FILL_BLOCKS, 256, 0, stream>>>(ei + N_EDGES, ghist_part);
  k_scan196<<<1, 256, 0, stream>>>(ghist_part, bro, pcur, rowp);
  k_partA<<<FILL_BLOCKS, 256, 0, stream>>>(ei, pcur, tmp);
  k_partB<<<NPART, 256, 0, stream>>>(tmp, bro, dis, rowp, eus);

  // layer 1
  k_gemm2<false><<<2048, 256, 0, stream>>>(x, W1, hW, statsL0, nullptr, gamma, beta);
  k_agg_node<<<nag, 256, 0, stream>>>(hW, dis, rowp, eus, b1, act, statsL0);
  // layer 2
  k_gemm2<true><<<2048, 256, 0, stream>>>(act, W2, hW, statsL1, statsL0, gamma, beta);
  k_agg_node<<<nag, 256, 0, stream>>>(hW, dis, rowp, eus, b2, act, statsL1);
  // layer 3
  k_gemm2<true><<<2048, 256, 0, stream>>>(act, W3, hW, statsL2, statsL1, gamma, beta);
  k_agg_node<<<nag, 256, 0, stream>>>(hW, dis, rowp, eus, b3, act, statsL2);

  k_pool_mlp<<<N_GRAPHS, 256, 0, stream>>>(act, statsL2, gamma, beta, l1w, l1b,
                                           l2w, l2b, out);
}

// Round 21
// 184.247 us; speedup vs baseline: 1.0228x; 1.0228x over previous
//
#include <hip/hip_runtime.h>
#include <hip/hip_bf16.h>

#define N_NODES 50000
#define N_EDGES 800000
#define HID 64
#define N_GRAPHS 64
#define N_CLASSES 10
#define BN_EPS 1e-5f
#define NPART 196          // ceil(50000/256) partitions of 256 dst nodes
#define FILL_BLOCKS 128

typedef unsigned int uint;
typedef unsigned short ushort;

__device__ __forceinline__ float blo(uint u) { return __uint_as_float(u << 16); }
__device__ __forceinline__ float bhi(uint u) { return __uint_as_float(u & 0xffff0000u); }
__device__ __forceinline__ unsigned short f2b(float f) {
  __hip_bfloat16 h = __float2bfloat16(f);
  return *reinterpret_cast<unsigned short*>(&h);
}

// ---------------- build ----------------

// per-chunk partial histograms of dst>>8: no zeroing, no global atomics
__global__ __launch_bounds__(256) void k_hist_part(const int* __restrict__ dst,
                                                   int* __restrict__ ghist_part) {
  __shared__ int l[NPART];
  int tid = threadIdx.x;
  for (int i = tid; i < NPART; i += 256) l[i] = 0;
  __syncthreads();
  const int per = (N_EDGES + FILL_BLOCKS - 1) / FILL_BLOCKS;
  int c0 = blockIdx.x * per;
  int c1 = c0 + per;
  if (c1 > N_EDGES) c1 = N_EDGES;
  for (int e = c0 + tid; e < c1; e += 256)
    atomicAdd(&l[__builtin_nontemporal_load(&dst[e]) >> 8], 1);
  __syncthreads();
  for (int p = tid; p < NPART; p += 256)
    ghist_part[blockIdx.x * NPART + p] = l[p];
}

// single block: sum 128 partials per partition, scan -> bro + pcur
__global__ void k_scan196(const int* __restrict__ ghist_part, int* __restrict__ bro,
                          int* __restrict__ pcur, int* __restrict__ rowp) {
  __shared__ int s[256];
  int tid = threadIdx.x;
  int v = 0;
  if (tid < NPART)
    for (int c = 0; c < FILL_BLOCKS; ++c) v += ghist_part[c * NPART + tid];
  s[tid] = v;
  __syncthreads();
  for (int off = 1; off < 256; off <<= 1) {
    int t = (tid >= off) ? s[tid - off] : 0;
    __syncthreads();
    s[tid] += t;
    __syncthreads();
  }
  if (tid < NPART) {
    int e = s[tid] - v;
    bro[tid] = e;
    pcur[tid] = e;
  }
  if (tid == 0) {
    bro[NPART] = N_EDGES;
    rowp[N_NODES] = N_EDGES;
  }
}

// Pass A: partition edges by dst>>8; per-block LDS histogram + reservation.
// tmp record = src<<8 | (dst & 255)  (24 bits used)
__global__ __launch_bounds__(256) void k_partA(const int* __restrict__ ei,
                                               int* __restrict__ pcur,
                                               uint* __restrict__ tmp) {
  __shared__ int lcnt[NPART];
  __shared__ int lbase[NPART];
  int tid = threadIdx.x;
  const int per = (N_EDGES + FILL_BLOCKS - 1) / FILL_BLOCKS;  // 6250
  int c0 = blockIdx.x * per;
  int c1 = c0 + per;
  if (c1 > N_EDGES) c1 = N_EDGES;
  for (int i = tid; i < NPART; i += 256) lcnt[i] = 0;
  __syncthreads();
  for (int e = c0 + tid; e < c1; e += 256) {
    int d = __builtin_nontemporal_load(&ei[N_EDGES + e]);
    atomicAdd(&lcnt[d >> 8], 1);
  }
  __syncthreads();
  for (int p = tid; p < NPART; p += 256) lbase[p] = atomicAdd(&pcur[p], lcnt[p]);
  __syncthreads();
  for (int e = c0 + tid; e < c1; e += 256) {
    int s = __builtin_nontemporal_load(&ei[e]);
    int d = __builtin_nontemporal_load(&ei[N_EDGES + e]);
    int pos = atomicAdd(&lbase[d >> 8], 1);
    tmp[pos] = ((uint)s << 8) | (uint)(d & 255);  // grouped runs: L2 merges
  }
}

// Pass B: one block per partition. Counts per-node degree (LDS), derives
// dis + rowp for its 256 nodes, then places ushort src records in final
// CSR order. All writes block-private -> fully merged.
__global__ __launch_bounds__(256) void k_partB(const uint* __restrict__ tmp,
                                               const int* __restrict__ bro,
                                               float* __restrict__ dis,
                                               int* __restrict__ rowp,
                                               ushort* __restrict__ eus) {
  __shared__ int cnt[256];
  __shared__ int s[256];
  __shared__ int cur[256];
  int tid = threadIdx.x;
  int p = blockIdx.x;
  int base = bro[p], pend = bro[p + 1];
  cnt[tid] = 0;
  __syncthreads();
  for (int idx = base + tid; idx < pend; idx += 256)
    atomicAdd(&cnt[__builtin_nontemporal_load(&tmp[idx]) & 255u], 1);
  __syncthreads();
  int deg = cnt[tid];
  int n = (p << 8) + tid;
  if (n < N_NODES) dis[n] = rsqrtf((float)deg + 1.0f);
  // exclusive scan of deg over 256
  s[tid] = deg;
  __syncthreads();
  for (int off = 1; off < 256; off <<= 1) {
    int t = (tid >= off) ? s[tid - off] : 0;
    __syncthreads();
    s[tid] += t;
    __syncthreads();
  }
  int start = base + s[tid] - deg;
  if (n < N_NODES) rowp[n] = start;
  cur[tid] = start;
  __syncthreads();
  for (int idx = base + tid; idx < pend; idx += 256) {
    uint t = __builtin_nontemporal_load(&tmp[idx]);
    int pos = atomicAdd(&cur[t & 255u], 1);
    eus[pos] = (ushort)(t >> 8);
  }
}

// ---------------- per-layer ----------------

// out16[n][j] = bf16( sum_k bnrelu(in[n][k]) * W[k][j] )
template <bool IN_BF16>
__global__ __launch_bounds__(256) void k_gemm(const void* __restrict__ in,
                                              const float* __restrict__ W,
                                              __hip_bfloat16* __restrict__ out,
                                              float* __restrict__ stats_zero,
                                              const float* __restrict__ stats_in,
                                              const float* __restrict__ gamma,
                                              const float* __restrict__ beta) {
  __shared__ float Al[4][64];
  int tid = threadIdx.x;
  int wid = tid >> 6, f = tid & 63;
  if (blockIdx.x == 0) {
    for (int i = tid; i < 1024; i += 256) stats_zero[i] = 0.0f;
  }
  float Wreg[64];
#pragma unroll
  for (int k = 0; k < 64; ++k) Wreg[k] = W[k * 64 + f];
  float sc = 1.f, sh = 0.f;
  if (stats_in) {
    float s = 0.f, q = 0.f;
#pragma unroll
    for (int c = 0; c < 8; ++c) {
      s += stats_in[c * 128 + f];
      q += stats_in[c * 128 + 64 + f];
    }
    float mu = s * (1.0f / N_NODES);
    float var = q * (1.0f / N_NODES) - mu * mu;
    sc = gamma[f] * rsqrtf(var + BN_EPS);
    sh = beta[f] - mu * sc;
  }
  for (int n = blockIdx.x * 4 + wid; n < N_NODES; n += gridDim.x * 4) {
    float av;
    if (IN_BF16) {
      ushort u = ((const ushort*)in)[(n << 6) + f];
      av = __uint_as_float((uint)u << 16);
    } else {
      av = ((const float*)in)[(n << 6) + f];
    }
    if (stats_in) {
      av = fmaf(av, sc, sh);
      av = av > 0.f ? av : 0.f;
    }
    Al[wid][f] = av;  // same-wave LDS: ordered, no barrier
    float acc = 0.f;
    const float4* arow = (const float4*)Al[wid];
#pragma unroll
    for (int k4 = 0; k4 < 16; ++k4) {
      float4 a = arow[k4];
      acc = fmaf(a.x, Wreg[k4 * 4 + 0], acc);
      acc = fmaf(a.y, Wreg[k4 * 4 + 1], acc);
      acc = fmaf(a.z, Wreg[k4 * 4 + 2], acc);
      acc = fmaf(a.w, Wreg[k4 * 4 + 3], acc);
    }
    out[(n << 6) + f] = __float2bfloat16(acc);  // cached: gather target
  }
}

// group-per-node aggregation: 8-lane group owns one node, lane owns 8 feats.
// ILP-8: all 8 row-gathers + 8 dis loads of a batch issued before any FMA
// consumes (hv[8] live). VGPR cap 128 (256,2): no spill.
__global__ __launch_bounds__(256, 2) void k_agg_node(
    const __hip_bfloat16* __restrict__ hW, const float* __restrict__ dis,
    const int* __restrict__ rowp, const ushort* __restrict__ eus,
    const float* __restrict__ bias, __hip_bfloat16* __restrict__ act,
    float* __restrict__ stats) {
  __shared__ float sstat[4][2][64];
  int tid = threadIdx.x;
  int wid = tid >> 6, lane = tid & 63;
  int g = lane >> 3, l8 = lane & 7;
  int n = (blockIdx.x * 4 + wid) * 8 + g;  // one node per 8-lane group
  const uint4* hw4 = (const uint4*)hW;
  float pre[8] = {0, 0, 0, 0, 0, 0, 0, 0};
  float sq[8] = {0, 0, 0, 0, 0, 0, 0, 0};
  if (n < N_NODES) {
    int p0 = rowp[n], p1 = rowp[n + 1];
    float dn = dis[n];
    uint4 hs = hw4[n * 8 + l8];  // hoisted self row: overlaps edge loop
    float acc[8] = {0, 0, 0, 0, 0, 0, 0, 0};
    for (int pb = p0; pb < p1; pb += 8) {
      int i0 = pb + l8;
      uint rs = (i0 < p1) ? (uint)eus[i0] : 0u;
      uint e8[8];
      float ds8[8];
      uint4 hv[8];
#pragma unroll
      for (int u = 0; u < 8; ++u) e8[u] = __shfl(rs, (g << 3) | u, 64);
#pragma unroll
      for (int u = 0; u < 8; ++u) {
        hv[u] = hw4[e8[u] * 8 + l8];  // 8 independent row gathers in flight
        ds8[u] = dis[e8[u]];          // L2-hot, co-issues
      }
#pragma unroll
      for (int u = 0; u < 8; ++u) {
        float wv = (pb + u < p1) ? ds8[u] * dn : 0.f;
        acc[0] = fmaf(blo(hv[u].x), wv, acc[0]);
        acc[1] = fmaf(bhi(hv[u].x), wv, acc[1]);
        acc[2] = fmaf(blo(hv[u].y), wv, acc[2]);
        acc[3] = fmaf(bhi(hv[u].y), wv, acc[3]);
        acc[4] = fmaf(blo(hv[u].z), wv, acc[4]);
        acc[5] = fmaf(bhi(hv[u].z), wv, acc[5]);
        acc[6] = fmaf(blo(hv[u].w), wv, acc[6]);
        acc[7] = fmaf(bhi(hv[u].w), wv, acc[7]);
      }
    }
    float dn2 = dn * dn;
    const float4* b4 = (const float4*)bias;
    float4 bA = b4[l8 * 2], bB = b4[l8 * 2 + 1];
    pre[0] = fmaf(blo(hs.x), dn2, acc[0]) + bA.x;
    pre[1] = fmaf(bhi(hs.x), dn2, acc[1]) + bA.y;
    pre[2] = fmaf(blo(hs.y), dn2, acc[2]) + bA.z;
    pre[3] = fmaf(bhi(hs.y), dn2, acc[3]) + bA.w;
    pre[4] = fmaf(blo(hs.z), dn2, acc[4]) + bB.x;
    pre[5] = fmaf(bhi(hs.z), dn2, acc[5]) + bB.y;
    pre[6] = fmaf(blo(hs.w), dn2, acc[6]) + bB.z;
    pre[7] = fmaf(bhi(hs.w), dn2, acc[7]) + bB.w;
    uint4 st;
    st.x = (uint)f2b(pre[0]) | ((uint)f2b(pre[1]) << 16);
    st.y = (uint)f2b(pre[2]) | ((uint)f2b(pre[3]) << 16);
    st.z = (uint)f2b(pre[4]) | ((uint)f2b(pre[5]) << 16);
    st.w = (uint)f2b(pre[6]) | ((uint)f2b(pre[7]) << 16);
    ((uint4*)act)[n * 8 + l8] = st;  // group stores contiguous 128B
#pragma unroll
    for (int i = 0; i < 8; ++i) sq[i] = pre[i] * pre[i];
  }
  // one cross-group reduce per wave
#pragma unroll
  for (int off = 8; off < 64; off <<= 1) {
#pragma unroll
    for (int i = 0; i < 8; ++i) {
      pre[i] += __shfl_xor(pre[i], off, 64);
      sq[i] += __shfl_xor(sq[i], off, 64);
    }
  }
  if (g == 0) {
#pragma unroll
    for (int i = 0; i < 8; ++i) {
      sstat[wid][0][l8 * 8 + i] = pre[i];
      sstat[wid][1][l8 * 8 + i] = sq[i];
    }
  }
  __syncthreads();
  if (tid < 128) {
    int which = tid >> 6, f = tid & 63;
    float s = sstat[0][which][f] + sstat[1][which][f] + sstat[2][which][f] +
              sstat[3][which][f];
    atomicAdd(&stats[(blockIdx.x & 7) * 128 + which * 64 + f], s);
  }
}

// ---------------- pool + MLP (fused) ----------------

__global__ __launch_bounds__(256) void k_pool_mlp(
    const __hip_bfloat16* __restrict__ act, const float* __restrict__ stats_in,
    const float* __restrict__ gamma, const float* __restrict__ beta,
    const float* __restrict__ w1, const float* __restrict__ b1,
    const float* __restrict__ w2, const float* __restrict__ b2,
    float* __restrict__ out) {
  int g = blockIdx.x;
  int tid = threadIdx.x;
  int l16 = tid & 15;  // feats 4*l16 .. 4*l16+3
  int r = tid >> 4;    // 16 row-slices
  float sc[4], sh[4];
#pragma unroll
  for (int i = 0; i < 4; ++i) {
    int f = l16 * 4 + i;
    float s = 0.f, q = 0.f;
#pragma unroll
    for (int c = 0; c < 8; ++c) {
      s += stats_in[c * 128 + f];
      q += stats_in[c * 128 + 64 + f];
    }
    float mu = s * (1.0f / N_NODES);
    float var = q * (1.0f / N_NODES) - mu * mu;
    sc[i] = gamma[f] * rsqrtf(var + BN_EPS);
    sh[i] = beta[f] - mu * sc[i];
  }
  int gs = g * N_NODES;
  int start = (gs + 63) >> 6;
  int end = (gs + N_NODES + 63) >> 6;
  float m[4] = {0.f, 0.f, 0.f, 0.f};  // post-ReLU >= 0
  const uint2* a2 = (const uint2*)act;
  for (int n = start + r; n < end; n += 16) {
    uint2 v = a2[n * 16 + l16];
    m[0] = fmaxf(m[0], fmaf(blo(v.x), sc[0], sh[0]));
    m[1] = fmaxf(m[1], fmaf(bhi(v.x), sc[1], sh[1]));
    m[2] = fmaxf(m[2], fmaf(blo(v.y), sc[2], sh[2]));
    m[3] = fmaxf(m[3], fmaf(bhi(v.y), sc[3], sh[3]));
  }
  __shared__ float sm[16][64];
#pragma unroll
  for (int i = 0; i < 4; ++i) sm[r][l16 * 4 + i] = m[i];
  __syncthreads();
  __shared__ float P[64];
  __shared__ float Hd[64];
  if (tid < 64) {
    float mm = sm[0][tid];
#pragma unroll
    for (int rr = 1; rr < 16; ++rr) mm = fmaxf(mm, sm[rr][tid]);
    P[tid] = mm;
  }
  __syncthreads();
  if (tid < 64) {
    float acc = b1[tid];
#pragma unroll
    for (int k = 0; k < 64; ++k) acc = fmaf(P[k], w1[k * 64 + tid], acc);
    Hd[tid] = acc > 0.f ? acc : 0.f;
  }
  __syncthreads();
  if (tid < N_CLASSES) {
    float acc = b2[tid];
#pragma unroll
    for (int k = 0; k < 64; ++k) acc = fmaf(Hd[k], w2[k * 10 + tid], acc);
    out[g * N_CLASSES + tid] = acc;
  }
}

// ---------------- launch ----------------

extern "C" void kernel_launch(void* const* d_in, const int* in_sizes, int n_in,
                              void* d_out, int out_size, void* d_ws, size_t ws_size,
                              hipStream_t stream) {
  const float* x = (const float*)d_in[0];
  const int* ei = (const int*)d_in[1];
  const float* W1 = (const float*)d_in[3];
  const float* b1 = (const float*)d_in[4];
  const float* W2 = (const float*)d_in[5];
  const float* b2 = (const float*)d_in[6];
  const float* W3 = (const float*)d_in[7];
  const float* b3 = (const float*)d_in[8];
  const float* gamma = (const float*)d_in[9];
  const float* beta = (const float*)d_in[10];
  const float* l1w = (const float*)d_in[11];
  const float* l1b = (const float*)d_in[12];
  const float* l2w = (const float*)d_in[13];
  const float* l2b = (const float*)d_in[14];
  float* out = (float*)d_out;

  char* ws = (char*)d_ws;
  size_t off = 0;
  auto alloc = [&](size_t bytes) {
    void* p = ws + off;
    off = (off + bytes + 255) & ~(size_t)255;
    return p;
  };
  int* ghist_part = (int*)alloc((size_t)FILL_BLOCKS * NPART * 4);
  int* bro = (int*)alloc((NPART + 1) * 4);
  int* pcur = (int*)alloc(NPART * 4);
  int* rowp = (int*)alloc((N_NODES + 1) * 4);
  uint* tmp = (uint*)alloc((size_t)N_EDGES * 4);
  ushort* eus = (ushort*)alloc((size_t)N_EDGES * 2 + 512);
  float* dis = (float*)alloc(N_NODES * 4);
  __hip_bfloat16* hW = (__hip_bfloat16*)alloc((size_t)N_NODES * 64 * 2);
  __hip_bfloat16* act = (__hip_bfloat16*)alloc((size_t)N_NODES * 64 * 2);
  float* statsL0 = (float*)alloc(1024 * 4);
  float* statsL1 = (float*)alloc(1024 * 4);
  float* statsL2 = (float*)alloc(1024 * 4);

  int nag = (N_NODES + 31) / 32;  // 1563 blocks, 1 node per 8-lane group

  k_hist_part<<<FILL_BLOCKS, 256, 0, stream>>>(ei + N_EDGES, ghist_part);
  k_scan196<<<1, 256, 0, stream>>>(ghist_part, bro, pcur, rowp);
  k_partA<<<FILL_BLOCKS, 256, 0, stream>>>(ei, pcur, tmp);
  k_partB<<<NPART, 256, 0, stream>>>(tmp, bro, dis, rowp, eus);

  // layer 1
  k_gemm<false><<<2048, 256, 0, stream>>>(x, W1, hW, statsL0, nullptr, gamma, beta);
  k_agg_node<<<nag, 256, 0, stream>>>(hW, dis, rowp, eus, b1, act, statsL0);
  // layer 2
  k_gemm<true><<<2048, 256, 0, stream>>>(act, W2, hW, statsL1, statsL0, gamma, beta);
  k_agg_node<<<nag, 256, 0, stream>>>(hW, dis, rowp, eus, b2, act, statsL1);
  // layer 3
  k_gemm<true><<<2048, 256, 0, stream>>>(act, W3, hW, statsL2, statsL1, gamma, beta);
  k_agg_node<<<nag, 256, 0, stream>>>(hW, dis, rowp, eus, b3, act, statsL2);

  k_pool_mlp<<<N_GRAPHS, 256, 0, stream>>>(act, statsL2, gamma, beta, l1w, l1b,
                                           l2w, l2b, out);
}